// Round 4
// baseline (420.102 us; speedup 1.0000x reference)
//
#include <hip/hip_runtime.h>
#include <math.h>

#define BSZ 8
#define MROWS 64
#define NCOLS 4096
#define KSEL 32
#define EPSF 1e-20f
#define NEG_INF (-3.402823466e+38f)

// DIAGNOSTIC ROUND: K2 re-sweeps its output slab REPEAT times (idempotent --
// final memory identical, absmax unaffected). This inflates K2 past the
// ~175us fillBufferAligned dispatches so it surfaces in the rocprof top-5
// and we finally see OUR dispatch's FETCH_SIZE / WRITE_SIZE / hbm_gbps.
// Next round drops REPEAT to 1.
#define REPEAT 5

typedef float floatx4 __attribute__((ext_vector_type(4)));

// ---------------------------------------------------------------------------
// Kernel 1: per-(b,m)-row top-32 selection (proven, unchanged from R2).
// 512 blocks; 4 waves stage swizzled LDS; wave 0 iterative top-32 + rank;
// writes 32 ascending-sorted indices per row to d_ws.
// ---------------------------------------------------------------------------
__global__ __launch_bounds__(256) void topk_select_kernel(
    const float* __restrict__ logits,   // (64, 4096)
    const float* __restrict__ u,        // (8, 64, 4096)
    int* __restrict__ idx_out)          // (8*64, 32)
{
    __shared__ float vals[NCOLS];       // 16 KiB

    const int r   = blockIdx.x;         // row = b*64 + m
    const int m   = r & (MROWS - 1);
    const int tid = threadIdx.x;

    const float4* u4 = (const float4*)(u + (size_t)r * NCOLS);
    const float4* l4 = (const float4*)(logits + (size_t)m * NCOLS);

    #pragma unroll
    for (int c = 0; c < 4; ++c) {
        int q = (c << 8) + tid;                  // float4 index, coalesced
        float4 uu = u4[q];
        float4 lg = l4[q];
        float px = lg.x - 0.001f * logf(-logf(uu.x + EPSF) + EPSF);
        float py = lg.y - 0.001f * logf(-logf(uu.y + EPSF) + EPSF);
        float pz = lg.z - 0.001f * logf(-logf(uu.z + EPSF) + EPSF);
        float pw = lg.w - 0.001f * logf(-logf(uu.w + EPSF) + EPSF);
        int col   = q << 2;
        int chunk = col >> 6;                    // same chunk for all 4 cols
        int base  = chunk << 6;
        vals[base + ((col + 0 + chunk) & 63)] = px;
        vals[base + ((col + 1 + chunk) & 63)] = py;
        vals[base + ((col + 2 + chunk) & 63)] = pz;
        vals[base + ((col + 3 + chunk) & 63)] = pw;
    }
    __syncthreads();

    const int lane = tid & 63;
    const int w    = tid >> 6;
    if (w != 0) return;                          // waves 1-3 done

    float lmax = NEG_INF;
    int   lidx = 0x7FFFFFFF;
    {
        const int cb = lane << 6;
        #pragma unroll 8
        for (int c = 0; c < 64; ++c) {           // ascending col => low-idx ties
            float v = vals[cb + ((c + lane) & 63)];
            if (v > lmax) { lmax = v; lidx = cb + c; }
        }
    }
    unsigned long long removed = 0ull;           // removal mask for OWN chunk
    int sel_reg = 0x7FFFFFFF;                    // lane i (<32) holds winner i
    for (int it = 0; it < KSEL; ++it) {
        float bv = lmax; int bi = lidx;
        #pragma unroll
        for (int off = 32; off; off >>= 1) {
            float ov = __shfl_xor(bv, off);
            int   oi = __shfl_xor(bi, off);
            if (ov > bv || (ov == bv && oi < bi)) { bv = ov; bi = oi; }
        }
        if (lane == it) sel_reg = bi;

        const int wl = bi >> 6;                  // winner chunk / owner lane
        if (lane == wl) removed |= (1ull << (bi & 63));

        unsigned long long rm = __shfl(removed, wl);
        float nv = vals[(wl << 6) + ((lane + wl) & 63)];
        int   ni = (wl << 6) + lane;
        if ((rm >> lane) & 1ull) nv = NEG_INF;
        #pragma unroll
        for (int off = 32; off; off >>= 1) {
            float ov = __shfl_xor(nv, off);
            int   oi = __shfl_xor(ni, off);
            if (ov > nv || (ov == nv && oi < ni)) { nv = ov; ni = oi; }
        }
        if (lane == wl) { lmax = nv; lidx = ni; }
    }
    int myw = sel_reg;
    int rank = 0;
    #pragma unroll
    for (int j = 0; j < KSEL; ++j) {
        int wj = __shfl(sel_reg, j);
        rank += (wj < myw) ? 1 : 0;
    }
    if (lane < KSEL) idx_out[(size_t)r * KSEL + rank] = myw;
}

// ---------------------------------------------------------------------------
// Kernel 2: fill-clone one-hot sweep.
// 256 blocks x 256 threads -- same shape/occupancy regime as the 6.4 TB/s
// fillBufferAligned (~9.7% occupancy => ~1 block/CU). Each block owns ONE
// contiguous 1 MiB slab (64 k-rows) and sweeps it strictly sequentially:
// one write front per CU. The 64 target indices are preloaded into wave
// registers (idx[rbase+lane]) and broadcast per row via __shfl -- zero
// scalar-load stalls in the store loop. The 1.0 is folded in by predication.
// ---------------------------------------------------------------------------
__global__ __launch_bounds__(256) void onehot_sweep_kernel(
    const int* __restrict__ idx,        // (8*64*32)
    float* __restrict__ out)            // (8, 64, 32, 4096)
{
    const int bid   = blockIdx.x;       // 0..255
    const int tid   = threadIdx.x;
    const int lane  = tid & 63;
    const int rbase = bid << 6;         // first of this block's 64 k-rows

    const int vidx = idx[rbase + lane]; // 64 row-targets live in wave regs
    floatx4* oblk = (floatx4*)out + ((size_t)rbase << 10);  // 1024 float4/row

    for (int rep = 0; rep < REPEAT; ++rep) {
        for (int j = 0; j < 64; ++j) {
            const int t  = __shfl(vidx, j);      // uniform broadcast
            const int tq = t >> 2;
            const int te = t & 3;
            floatx4* orow = oblk + ((size_t)j << 10);
            #pragma unroll
            for (int c = 0; c < 4; ++c) {
                int q = (c << 8) + tid;          // float4 index, coalesced
                bool hit = (q == tq);
                floatx4 z;
                z.x = (hit && te == 0) ? 1.0f : 0.0f;
                z.y = (hit && te == 1) ? 1.0f : 0.0f;
                z.z = (hit && te == 2) ? 1.0f : 0.0f;
                z.w = (hit && te == 3) ? 1.0f : 0.0f;
                orow[q] = z;
            }
        }
    }
}

extern "C" void kernel_launch(void* const* d_in, const int* in_sizes, int n_in,
                              void* d_out, int out_size, void* d_ws, size_t ws_size,
                              hipStream_t stream) {
    const float* logits = (const float*)d_in[0];   // (64, 4096) fp32
    const float* u      = (const float*)d_in[1];   // (8, 64, 4096) fp32
    float* out          = (float*)d_out;           // (8, 64, 32, 4096) fp32
    int* idx            = (int*)d_ws;              // 64 KiB of workspace

    topk_select_kernel<<<BSZ * MROWS, 256, 0, stream>>>(logits, u, idx);
    onehot_sweep_kernel<<<256, 256, 0, stream>>>(idx, out);
}

// Round 5
// 299.454 us; speedup vs baseline: 1.4029x; 1.4029x over previous
//
#include <hip/hip_runtime.h>
#include <math.h>

#define BSZ 8
#define MROWS 64
#define NCOLS 4096
#define KSEL 32
#define EPSF 1e-20f
#define NEG_INF (-3.402823466e+38f)

typedef float floatx4 __attribute__((ext_vector_type(4)));

// ---------------------------------------------------------------------------
// Kernel 1: per-(b,m)-row top-32 selection (proven).
// 512 blocks; 4 waves stage swizzled LDS; wave 0 iterative top-32 + rank;
// writes 32 ascending-sorted indices per row to d_ws.
//
// Swizzle: column col lives at (col & ~63) | ((col + (col>>6)) & 63).
// Lane l owns chunk [64l, 64l+64). Per-lane chunk scan and all-lanes
// single-chunk rescan are both 2-lanes-per-bank (free on gfx950, m136).
// ---------------------------------------------------------------------------
__global__ __launch_bounds__(256) void topk_select_kernel(
    const float* __restrict__ logits,   // (64, 4096)
    const float* __restrict__ u,        // (8, 64, 4096)
    int* __restrict__ idx_out)          // (8*64, 32)
{
    __shared__ float vals[NCOLS];       // 16 KiB

    const int r   = blockIdx.x;         // row = b*64 + m
    const int m   = r & (MROWS - 1);
    const int tid = threadIdx.x;

    const float4* u4 = (const float4*)(u + (size_t)r * NCOLS);
    const float4* l4 = (const float4*)(logits + (size_t)m * NCOLS);

    #pragma unroll
    for (int c = 0; c < 4; ++c) {
        int q = (c << 8) + tid;                  // float4 index, coalesced
        float4 uu = u4[q];
        float4 lg = l4[q];
        float px = lg.x - 0.001f * logf(-logf(uu.x + EPSF) + EPSF);
        float py = lg.y - 0.001f * logf(-logf(uu.y + EPSF) + EPSF);
        float pz = lg.z - 0.001f * logf(-logf(uu.z + EPSF) + EPSF);
        float pw = lg.w - 0.001f * logf(-logf(uu.w + EPSF) + EPSF);
        int col   = q << 2;
        int chunk = col >> 6;                    // same chunk for all 4 cols
        int base  = chunk << 6;
        vals[base + ((col + 0 + chunk) & 63)] = px;
        vals[base + ((col + 1 + chunk) & 63)] = py;
        vals[base + ((col + 2 + chunk) & 63)] = pz;
        vals[base + ((col + 3 + chunk) & 63)] = pw;
    }
    __syncthreads();

    const int lane = tid & 63;
    const int w    = tid >> 6;
    if (w != 0) return;                          // waves 1-3 done

    float lmax = NEG_INF;
    int   lidx = 0x7FFFFFFF;
    {
        const int cb = lane << 6;
        #pragma unroll 8
        for (int c = 0; c < 64; ++c) {           // ascending col => low-idx ties
            float v = vals[cb + ((c + lane) & 63)];
            if (v > lmax) { lmax = v; lidx = cb + c; }
        }
    }
    unsigned long long removed = 0ull;           // removal mask for OWN chunk
    int sel_reg = 0x7FFFFFFF;                    // lane i (<32) holds winner i
    for (int it = 0; it < KSEL; ++it) {
        float bv = lmax; int bi = lidx;
        #pragma unroll
        for (int off = 32; off; off >>= 1) {
            float ov = __shfl_xor(bv, off);
            int   oi = __shfl_xor(bi, off);
            if (ov > bv || (ov == bv && oi < bi)) { bv = ov; bi = oi; }
        }
        if (lane == it) sel_reg = bi;

        const int wl = bi >> 6;                  // winner chunk / owner lane
        if (lane == wl) removed |= (1ull << (bi & 63));

        unsigned long long rm = __shfl(removed, wl);
        float nv = vals[(wl << 6) + ((lane + wl) & 63)];
        int   ni = (wl << 6) + lane;
        if ((rm >> lane) & 1ull) nv = NEG_INF;
        #pragma unroll
        for (int off = 32; off; off >>= 1) {
            float ov = __shfl_xor(nv, off);
            int   oi = __shfl_xor(ni, off);
            if (ov > nv || (ov == nv && oi < ni)) { nv = ov; ni = oi; }
        }
        if (lane == wl) { lmax = nv; lidx = ni; }
    }
    int myw = sel_reg;
    int rank = 0;
    #pragma unroll
    for (int j = 0; j < KSEL; ++j) {
        int wj = __shfl(sel_reg, j);
        rank += (wj < myw) ? 1 : 0;
    }
    if (lane < KSEL) idx_out[(size_t)r * KSEL + rank] = myw;
}

// ---------------------------------------------------------------------------
// Kernel 2: one-hot sweep in the 97%-of-peak-BW structure (measured R4:
// 7.76-7.84 TB/s, WRITE_SIZE exact, no RFO).
// 256 blocks x 256 threads = exactly ONE block per CU. Each block owns ONE
// contiguous 1 MiB slab (64 k-rows) and sweeps it strictly sequentially --
// one 16 KiB-wide write front per CU. The 64 target indices are preloaded
// into wave registers (idx[rbase+lane]) and broadcast per row via __shfl;
// the 1.0 is folded into the stream by predication (no second pass).
// DO NOT change this structure: 6-24 scattered fronts/CU measured 2.5-3x
// slower (R1-R3); nt-stores and block fattening were epicycles.
// ---------------------------------------------------------------------------
__global__ __launch_bounds__(256) void onehot_sweep_kernel(
    const int* __restrict__ idx,        // (8*64*32)
    float* __restrict__ out)            // (8, 64, 32, 4096)
{
    const int bid   = blockIdx.x;       // 0..255
    const int tid   = threadIdx.x;
    const int lane  = tid & 63;
    const int rbase = bid << 6;         // first of this block's 64 k-rows

    const int vidx = idx[rbase + lane]; // 64 row-targets live in wave regs
    floatx4* oblk = (floatx4*)out + ((size_t)rbase << 10);  // 1024 float4/row

    for (int j = 0; j < 64; ++j) {
        const int t  = __shfl(vidx, j);      // uniform broadcast
        const int tq = t >> 2;
        const int te = t & 3;
        floatx4* orow = oblk + ((size_t)j << 10);
        #pragma unroll
        for (int c = 0; c < 4; ++c) {
            int q = (c << 8) + tid;          // float4 index, coalesced
            bool hit = (q == tq);
            floatx4 z;
            z.x = (hit && te == 0) ? 1.0f : 0.0f;
            z.y = (hit && te == 1) ? 1.0f : 0.0f;
            z.z = (hit && te == 2) ? 1.0f : 0.0f;
            z.w = (hit && te == 3) ? 1.0f : 0.0f;
            orow[q] = z;
        }
    }
}

extern "C" void kernel_launch(void* const* d_in, const int* in_sizes, int n_in,
                              void* d_out, int out_size, void* d_ws, size_t ws_size,
                              hipStream_t stream) {
    const float* logits = (const float*)d_in[0];   // (64, 4096) fp32
    const float* u      = (const float*)d_in[1];   // (8, 64, 4096) fp32
    float* out          = (float*)d_out;           // (8, 64, 32, 4096) fp32
    int* idx            = (int*)d_ws;              // 64 KiB of workspace

    topk_select_kernel<<<BSZ * MROWS, 256, 0, stream>>>(logits, u, idx);
    onehot_sweep_kernel<<<256, 256, 0, stream>>>(idx, out);
}

// Round 6
// 296.164 us; speedup vs baseline: 1.4185x; 1.0111x over previous
//
#include <hip/hip_runtime.h>
#include <math.h>

#define BSZ 8
#define MROWS 64
#define NCOLS 4096
#define KSEL 32
#define EPSF 1e-20f
#define NEG_INF (-3.402823466e+38f)

typedef float floatx4 __attribute__((ext_vector_type(4)));

// ---------------------------------------------------------------------------
// Fully fused top-32 one-hot, built around the MEASURED 97%-of-peak write
// structure (R4: 7.76-7.84 TB/s, WRITE_SIZE exact, no RFO):
//   256 blocks x 256 threads = one block per CU, each owning ONE contiguous
//   1 MiB output slab (64 k-rows = 2 (b,m)-rows x 32 k), swept strictly
//   sequentially as ONE write front per CU.
//
//   waves 2-3 : zero-sweep the whole slab starting at cycle 0 (the sweep
//               needs no indices -- ones are scattered afterwards).
//   wave 0/1  : stage + select row 2*bid + w (verbatim proven selection;
//               single-wave staging->scan relies on the in-order per-wave
//               DS pipe, validated in R3). Finishes ~15us, hidden under
//               the ~35-45us sweep.
//   barrier   : sweep drained + si visible.
//   wave 0    : 64 lanes scatter the 64 ones (dword stores, ~2 MiB RFO
//               total across the grid -- negligible).
//
// DO NOT re-split or multiply write fronts: 6-24 scattered fronts/CU
// measured 2.5-3x slower (R0-R3); a separate selection kernel costs
// ~100us of serial makespan (R1/R2/R5).
//
// Swizzle: column col lives at (col & ~63) | ((col + (col>>6)) & 63).
// Lane l owns chunk [64l, 64l+64). Per-lane chunk scan and all-lanes
// single-chunk rescan are both 2-lanes-per-bank (free on gfx950, m136).
// ---------------------------------------------------------------------------
__global__ __launch_bounds__(256) void topk_onehot_kernel(
    const float* __restrict__ logits,   // (64, 4096)
    const float* __restrict__ u,        // (8, 64, 4096)
    float* __restrict__ out)            // (8, 64, 32, 4096)
{
    __shared__ float vals[2][NCOLS];    // 32 KiB (one row buffer per sel wave)
    __shared__ int   si[2 * KSEL];      // 64 sorted winner columns

    const int bid  = blockIdx.x;        // 0..255
    const int tid  = threadIdx.x;
    const int lane = tid & 63;
    const int w    = tid >> 6;

    if (w >= 2) {
        // ---- waves 2-3: one sequential zero front over the 1 MiB slab ----
        const int z = tid - 128;                         // 0..127
        floatx4* oblk = (floatx4*)out + ((size_t)bid << 16);  // 64 rows * 1024 f4
        const floatx4 z4 = {0.f, 0.f, 0.f, 0.f};
        for (int j = 0; j < 64; ++j) {                   // row-by-row, ascending
            floatx4* orow = oblk + (j << 10);
            #pragma unroll
            for (int c = 0; c < 8; ++c)                  // 2 KiB steps, ascending
                orow[(c << 7) + z] = z4;
        }
    } else {
        // ---- wave w (0/1): stage + select row r = 2*bid + w ----
        const int r = (bid << 1) + w;
        const int m = r & (MROWS - 1);
        float* v = vals[w];
        const float4* u4 = (const float4*)(u + (size_t)r * NCOLS);
        const float4* l4 = (const float4*)(logits + (size_t)m * NCOLS);

        #pragma unroll
        for (int c = 0; c < 16; ++c) {
            int q = (c << 6) + lane;                 // float4 index, coalesced
            float4 uu = u4[q];
            float4 lg = l4[q];
            float px = lg.x - 0.001f * logf(-logf(uu.x + EPSF) + EPSF);
            float py = lg.y - 0.001f * logf(-logf(uu.y + EPSF) + EPSF);
            float pz = lg.z - 0.001f * logf(-logf(uu.z + EPSF) + EPSF);
            float pw = lg.w - 0.001f * logf(-logf(uu.w + EPSF) + EPSF);
            int col   = q << 2;
            int chunk = col >> 6;                    // same chunk for all 4 cols
            int base  = chunk << 6;
            v[base + ((col + 0 + chunk) & 63)] = px;
            v[base + ((col + 1 + chunk) & 63)] = py;
            v[base + ((col + 2 + chunk) & 63)] = pz;
            v[base + ((col + 3 + chunk) & 63)] = pw;
        }
        // single-wave staging -> scan: per-wave DS pipe is in-order, no
        // barrier needed (validated in R3, absmax 0).

        float lmax = NEG_INF;
        int   lidx = 0x7FFFFFFF;
        {
            const int cb = lane << 6;
            #pragma unroll 8
            for (int c = 0; c < 64; ++c) {           // ascending col => low-idx ties
                float x = v[cb + ((c + lane) & 63)];
                if (x > lmax) { lmax = x; lidx = cb + c; }
            }
        }
        unsigned long long removed = 0ull;           // removal mask for OWN chunk
        int sel_reg = 0x7FFFFFFF;                    // lane i (<32) holds winner i
        for (int it = 0; it < KSEL; ++it) {
            float bv = lmax; int bi = lidx;
            #pragma unroll
            for (int off = 32; off; off >>= 1) {
                float ov = __shfl_xor(bv, off);
                int   oi = __shfl_xor(bi, off);
                if (ov > bv || (ov == bv && oi < bi)) { bv = ov; bi = oi; }
            }
            if (lane == it) sel_reg = bi;

            const int wl = bi >> 6;                  // winner chunk / owner lane
            if (lane == wl) removed |= (1ull << (bi & 63));

            unsigned long long rm = __shfl(removed, wl);
            float nv = v[(wl << 6) + ((lane + wl) & 63)];
            int   ni = (wl << 6) + lane;
            if ((rm >> lane) & 1ull) nv = NEG_INF;
            #pragma unroll
            for (int off = 32; off; off >>= 1) {
                float ov = __shfl_xor(nv, off);
                int   oi = __shfl_xor(ni, off);
                if (ov > nv || (ov == nv && oi < ni)) { nv = ov; ni = oi; }
            }
            if (lane == wl) { lmax = nv; lidx = ni; }
        }
        // rank = ascending position (winners distinct)
        int myw = sel_reg;
        int rank = 0;
        #pragma unroll
        for (int j = 0; j < KSEL; ++j) {
            int wj = __shfl(sel_reg, j);
            rank += (wj < myw) ? 1 : 0;
        }
        if (lane < KSEL) si[(w << 5) + rank] = myw;  // same-wave DS pipe: in-order
    }

    __syncthreads();   // sweep drained (vmcnt(0) before s_barrier) + si visible

    // ---- scatter the 64 ones over the zeroed slab ----
    if (tid < 64) {
        // global k-row (bid*64 + j) has its 1 at column si[j]
        out[((size_t)(bid << 6) + tid) * NCOLS + (size_t)si[tid]] = 1.0f;
    }
}

extern "C" void kernel_launch(void* const* d_in, const int* in_sizes, int n_in,
                              void* d_out, int out_size, void* d_ws, size_t ws_size,
                              hipStream_t stream) {
    const float* logits = (const float*)d_in[0];   // (64, 4096) fp32
    const float* u      = (const float*)d_in[1];   // (8, 64, 4096) fp32
    float* out          = (float*)d_out;           // (8, 64, 32, 4096) fp32

    topk_onehot_kernel<<<256, 256, 0, stream>>>(logits, u, out);
}